// Round 8
// baseline (290.476 us; speedup 1.0000x reference)
//
#include <hip/hip_runtime.h>
#include <hip/hip_bf16.h>
#include <math.h>

typedef __bf16 bf16_8 __attribute__((ext_vector_type(8)));
typedef float f32x4 __attribute__((ext_vector_type(4)));

#define D_ 256
#define S_ 128
#define E_ 512
#define MPE_ 4096
#define B_ 2
#define N_ 4096
#define M_TOT (B_*N_)   // 8192

__device__ __forceinline__ ushort f2b(float f) {
  union { float f; uint u; } x; x.f = f;
  uint r = (x.u + 0x7FFFu + ((x.u >> 16) & 1u)) >> 16;
  return (ushort)r;
}
__device__ __forceinline__ float b2f(ushort b) {
  union { uint u; float f; } x; x.u = ((uint)b) << 16;
  return x.f;
}

__device__ __forceinline__ void gl_lds16(const void* g, void* l) {
  __builtin_amdgcn_global_load_lds(
      (const __attribute__((address_space(1))) void*)g,
      (__attribute__((address_space(3))) void*)l, 16, 0, 0);
}

// ---------------- LayerNorm: one wave per row ----------------
__global__ __launch_bounds__(256) void ln_kernel(const float* __restrict__ q,
    const float* __restrict__ w, const float* __restrict__ b,
    ushort* __restrict__ x) {
  int wid = threadIdx.x >> 6, lane = threadIdx.x & 63;
  int row = blockIdx.x * 4 + wid;
  const float* qr = q + (size_t)row * D_;
  float4 v = *(const float4*)(qr + lane * 4);
  float s  = v.x + v.y + v.z + v.w;
  float ss = v.x*v.x + v.y*v.y + v.z*v.z + v.w*v.w;
  #pragma unroll
  for (int off = 32; off; off >>= 1) {
    s  += __shfl_xor(s, off);
    ss += __shfl_xor(ss, off);
  }
  float mu   = s * (1.0f / 256.0f);
  float var  = ss * (1.0f / 256.0f) - mu * mu;
  float rstd = rsqrtf(var + 1e-5f);
  ushort4 o;
  float vv[4] = {v.x, v.y, v.z, v.w};
  ushort ot[4];
  #pragma unroll
  for (int j = 0; j < 4; ++j) {
    int c = lane * 4 + j;
    ot[j] = f2b((vv[j] - mu) * rstd * w[c] + b[c]);
  }
  o.x = ot[0]; o.y = ot[1]; o.z = ot[2]; o.w = ot[3];
  *(ushort4*)(x + (size_t)row * D_ + lane * 4) = o;
}

// ---------------- weight transpose + cast ----------------
__global__ void wt_kernel(const float* __restrict__ in, ushort* __restrict__ out,
                          int R, int C) {
  int o = blockIdx.x * 256 + threadIdx.x;
  if (o >= R * C) return;
  int c = o / R, r = o - c * R;
  out[o] = f2b(in[r * C + c]);
}

// ---------------- bias replicate: wrep[c][i] = w_rel[min(i+c,8190)], c=0..3 ----------------
__global__ __launch_bounds__(256) void wrep_kernel(const float* __restrict__ w_rel,
                                                   float* __restrict__ wrep) {
  int idx = blockIdx.x * 256 + threadIdx.x;   // 0..32767
  int c = idx >> 13, i = idx & 8191;
  int s = i + c; if (s > 8190) s = 8190;
  wrep[idx] = w_rel[s];
}

// ---------------- GEMM: A[M][K] bf16, Bt[N][K] bf16, tile 128x64, BK=64 ----------------
template<int EPI>
__global__ __launch_bounds__(256) void gemm_kernel(
    const ushort* __restrict__ A, const ushort* __restrict__ Bt,
    const float* __restrict__ bias, void* __restrict__ out,
    int M, int N, int K) {
  __shared__ alignas(16) ushort As[128 * 64];
  __shared__ alignas(16) ushort Bs[64 * 64];
  int tid = threadIdx.x;
  int lane = tid & 63, wid = tid >> 6;
  int m0 = blockIdx.x * 128, n0 = blockIdx.y * 64;
  int r16 = lane & 15, kq = lane >> 4;
  f32x4 acc[2][4] = {};
  for (int k0 = 0; k0 < K; k0 += 64) {
    __syncthreads();
    #pragma unroll
    for (int t = 0; t < 4; ++t) {
      int cid = tid + t * 256;
      int row = cid >> 3, c = cid & 7;
      uint4 d = *(const uint4*)(A + ((size_t)(m0 + row) * K + k0 + c * 8));
      *(uint4*)&As[row * 64 + ((c ^ (row & 7)) * 8)] = d;
    }
    #pragma unroll
    for (int t = 0; t < 2; ++t) {
      int cid = tid + t * 256;
      int row = cid >> 3, c = cid & 7;
      uint4 d = *(const uint4*)(Bt + ((size_t)(n0 + row) * K + k0 + c * 8));
      *(uint4*)&Bs[row * 64 + ((c ^ (row & 7)) * 8)] = d;
    }
    __syncthreads();
    #pragma unroll
    for (int ks = 0; ks < 2; ++ks) {
      bf16_8 af[2], bfr[4];
      int c = ks * 4 + kq;
      #pragma unroll
      for (int fm = 0; fm < 2; ++fm) {
        int r = wid * 32 + fm * 16 + r16;
        af[fm] = *(const bf16_8*)&As[r * 64 + ((c ^ (r & 7)) * 8)];
      }
      #pragma unroll
      for (int fn = 0; fn < 4; ++fn) {
        int r = fn * 16 + r16;
        bfr[fn] = *(const bf16_8*)&Bs[r * 64 + ((c ^ (r & 7)) * 8)];
      }
      #pragma unroll
      for (int fm = 0; fm < 2; ++fm)
        #pragma unroll
        for (int fn = 0; fn < 4; ++fn)
          acc[fm][fn] = __builtin_amdgcn_mfma_f32_16x16x32_bf16(af[fm], bfr[fn], acc[fm][fn], 0, 0, 0);
    }
  }
  #pragma unroll
  for (int fm = 0; fm < 2; ++fm)
    #pragma unroll
    for (int fn = 0; fn < 4; ++fn)
      #pragma unroll
      for (int reg = 0; reg < 4; ++reg) {
        int ml = wid * 32 + fm * 16 + kq * 4 + reg;
        int nl = fn * 16 + r16;
        size_t gm = m0 + ml, gn = n0 + nl;
        float val = acc[fm][fn][reg] + bias[gn];
        if (EPI == 0) {
          float y = val / (1.0f + expf(-val));
          ((ushort*)out)[gm * N + gn] = f2b(y);
        } else if (EPI == 2) {
          float y = val / (1.0f + expf(-val));
          ((ushort*)out)[gn * (size_t)M_TOT + gm] = f2b(y);
        } else {
          ((float*)out)[gm * N + gn] = val;
        }
      }
}

// ---------------- RoPE (outputs pre-scaled by 1/64 so q.k carries 1/MPE) ----------------
__global__ __launch_bounds__(256) void rope_kernel(const ushort* __restrict__ base,
    const float* __restrict__ qw, const float* __restrict__ qb,
    const float* __restrict__ kw, const float* __restrict__ kb,
    ushort* __restrict__ Q, ushort* __restrict__ Kk) {
  int g = blockIdx.x * 256 + threadIdx.x;
  int row = g >> 6, i = g & 63;
  int n = row & (N_ - 1);
  float invf = powf(10000.0f, -(float)i * (1.0f / 64.0f));
  float sv, cv;
  sincosf((float)n * invf, &sv, &cv);
  const float sc = 0.015625f;   // 1/64; (1/64)^2 = 1/4096 = 1/MPE
  float b1 = b2f(base[row * S_ + i]), b2 = b2f(base[row * S_ + 64 + i]);
  float x1q = b1 * qw[i] + qb[i], x2q = b2 * qw[64 + i] + qb[64 + i];
  Q[row * S_ + i]      = f2b((x1q * cv - x2q * sv) * sc);
  Q[row * S_ + 64 + i] = f2b((x2q * cv + x1q * sv) * sc);
  float x1k = b1 * kw[i] + kb[i], x2k = b2 * kw[64 + i] + kb[64 + i];
  Kk[row * S_ + i]      = f2b((x1k * cv - x2k * sv) * sc);
  Kk[row * S_ + 64 + i] = f2b((x2k * cv + x1k * sv) * sc);
}

// ---------------- fused attention: V-from-global (T14), bias float4, K dbuf ----------------
// grid (32 m-tiles of 128, 4 e-chunks of 128, 2 b), 512 thr (8 waves), 1 block/CU.
// LDS only K (double-buffered) + P (double-buffered) = 64KB. V fragments loaded
// straight from global VT into registers at body start (L1/L2-resident tile),
// consumed by PV(t-1) mid-body. Bias: one aligned dwordx4 per fm via wrep copies.
__global__ __launch_bounds__(512, 2) void attn_kernel(
    const ushort* __restrict__ Q, const ushort* __restrict__ Kd,
    const ushort* __restrict__ VT, const ushort* __restrict__ U,
    const float* __restrict__ wrep, ushort* __restrict__ KVU) {
  __shared__ alignas(16) ushort Ks[2][64 * 128];   // 32 KB
  __shared__ alignas(16) ushort Pb[2][128 * 64];   // 32 KB
  const int tid = threadIdx.x, lane = tid & 63, wid = tid >> 6;
  const int b = blockIdx.z, m0 = blockIdx.x * 128, e0 = blockIdx.y * 128;
  const int r16 = lane & 15, kq = lane >> 4;
  const int wqm = wid >> 2, wqn = wid & 3;   // QK: 2m x 4n
  const int wpm = wid >> 1, wpe = wid & 1;   // PV: 4m x 2e

  // bias base: index = BI + 64t - 16fm into w_rel; csel = BI&3 (lane-const)
  const int BI = 4095 + 16 * wqn + 4 * kq - m0 - 64 * wqm - r16;
  const int csel = BI & 3;
  const float* wrow = wrep + csel * 8192 + (BI - csel);

  // Q fragments: wave's 64 m-rows x 128 k (B-operand: col=m)
  bf16_8 qf[4][4];
  #pragma unroll
  for (int fm = 0; fm < 4; ++fm)
    #pragma unroll
    for (int ks = 0; ks < 4; ++ks)
      qf[fm][ks] = *(const bf16_8*)(Q +
          ((size_t)(b * N_ + m0 + wqm * 64 + fm * 16 + r16) * S_ + ks * 32 + kq * 8));

  auto stage_k = [&](int bi, int nt) {
    int n0s = nt * 64;
    #pragma unroll
    for (int tt = 0; tt < 2; ++tt) {           // K tile: 64n x 128s = 1024 chunks
      int p = tt * 512 + tid;
      int row = p >> 4, sc2 = p & 15;
      int cc = sc2 ^ (row & 7);
      gl_lds16(Kd + ((size_t)(b * N_ + n0s + row) * S_ + cc * 8),
               &Ks[bi][(tt * 512 + wid * 64) * 8]);
    }
  };

  uint4 vfr[8];
  auto issue_vf = [&](int nt) {                // V frags for tile nt -> registers
    int n0s = nt * 64;
    #pragma unroll
    for (int ks = 0; ks < 2; ++ks)
      #pragma unroll
      for (int fe = 0; fe < 4; ++fe) {
        int rv = wpe * 64 + fe * 16 + r16;
        int cv = ks * 4 + kq;
        vfr[ks * 4 + fe] = *(const uint4*)(VT +
            (size_t)(e0 + rv) * M_TOT + b * N_ + n0s + cv * 8);
      }
  };

  f32x4 pv[2][4] = {};

  auto do_pv = [&](const ushort* pr) {
    __builtin_amdgcn_s_setprio(1);
    #pragma unroll
    for (int ks = 0; ks < 2; ++ks) {
      bf16_8 pa[2];
      #pragma unroll
      for (int fm = 0; fm < 2; ++fm) {
        int r = wpm * 32 + fm * 16 + r16;
        pa[fm] = *(const bf16_8*)((const char*)pr + ((r * 128 + ks * 64 + kq * 16) ^ ((r & 7) << 4)));
      }
      #pragma unroll
      for (int fe = 0; fe < 4; ++fe) {
        bf16_8 vf = *(const bf16_8*)&vfr[ks * 4 + fe];
        #pragma unroll
        for (int fm = 0; fm < 2; ++fm)
          pv[fm][fe] = __builtin_amdgcn_mfma_f32_16x16x32_bf16(pa[fm], vf, pv[fm][fe], 0, 0, 0);
      }
    }
    __builtin_amdgcn_s_setprio(0);
  };

  // prologue: K(0)
  stage_k(0, 0);
  asm volatile("s_waitcnt vmcnt(0) lgkmcnt(0)" ::: "memory");
  __builtin_amdgcn_s_barrier();

  for (int t = 0; t < 64; ++t) {
    const int CUR = t & 1;
    // ---- issue V(t-1) frags + bias(t) + K(t+1) stage (all VMEM, early) ----
    if (t > 0) issue_vf(t - 1);
    float4 b4[4];
    #pragma unroll
    for (int fm = 0; fm < 4; ++fm)
      b4[fm] = *(const float4*)(wrow + 64 * t - 16 * fm);
    if (t < 63) stage_k(CUR ^ 1, t + 1);
    __builtin_amdgcn_sched_barrier(0);
    // ---- QK (swapped): sacc[fm] = K_frag x Q_frag -> col=m, rows=n ----
    const ushort* ksb = Ks[CUR];
    f32x4 sacc[4] = {};
    __builtin_amdgcn_s_setprio(1);
    #pragma unroll
    for (int ks = 0; ks < 4; ++ks) {
      int r = wqn * 16 + r16;
      int c = ks * 4 + kq;
      bf16_8 kf = *(const bf16_8*)&ksb[r * 128 + ((c ^ (r & 7)) * 8)];
      #pragma unroll
      for (int fm = 0; fm < 4; ++fm)
        sacc[fm] = __builtin_amdgcn_mfma_f32_16x16x32_bf16(kf, qf[fm][ks], sacc[fm], 0, 0, 0);
    }
    __builtin_amdgcn_s_setprio(0);
    // ---- PV over previous tile (vfr registers + Pb[CUR^1]) ----
    if (t > 0) do_pv((const ushort*)&Pb[CUR ^ 1][0]);
    // ---- transform -> Pb[CUR] (packed uint2 writes) ----
    char* psb = (char*)&Pb[CUR][0];
    #pragma unroll
    for (int fm = 0; fm < 4; ++fm) {
      float t0 = fmaxf(sacc[fm][0] + b4[fm].x, 0.f);
      float t1 = fmaxf(sacc[fm][1] + b4[fm].y, 0.f);
      float t2 = fmaxf(sacc[fm][2] + b4[fm].z, 0.f);
      float t3 = fmaxf(sacc[fm][3] + b4[fm].w, 0.f);
      t0 *= t0; t1 *= t1; t2 *= t2; t3 *= t3;
      uint p01, p23;
      asm("v_cvt_pk_bf16_f32 %0, %1, %2" : "=v"(p01) : "v"(t0), "v"(t1));
      asm("v_cvt_pk_bf16_f32 %0, %1, %2" : "=v"(p23) : "v"(t2), "v"(t3));
      int mp = wqm * 64 + fm * 16 + r16;
      int nb2 = wqn * 32 + kq * 8;
      uint2 pk; pk.x = p01; pk.y = p23;
      *(uint2*)(psb + ((mp * 128 + nb2) ^ ((mp & 7) << 4))) = pk;
    }
    asm volatile("s_waitcnt vmcnt(0) lgkmcnt(0)" ::: "memory");
    __builtin_amdgcn_s_barrier();
  }
  // drain: PV for tile 63
  issue_vf(63);
  do_pv((const ushort*)&Pb[1][0]);

  // ---- epilogue: KVU = bf16(u * pv) ----
  #pragma unroll
  for (int fm = 0; fm < 2; ++fm)
    #pragma unroll
    for (int fe = 0; fe < 4; ++fe)
      #pragma unroll
      for (int reg = 0; reg < 4; ++reg) {
        int ml = wpm * 32 + fm * 16 + kq * 4 + reg;
        size_t grow = (size_t)b * N_ + m0 + ml;
        size_t ge = e0 + wpe * 64 + fe * 16 + r16;
        float uu = b2f(U[grow * E_ + ge]);
        KVU[grow * E_ + ge] = f2b(uu * pv[fm][fe][reg]);
      }
}

extern "C" void kernel_launch(void* const* d_in, const int* in_sizes, int n_in,
                              void* d_out, int out_size, void* d_ws, size_t ws_size,
                              hipStream_t stream) {
  const float* query = (const float*)d_in[0];
  const float* ln_w  = (const float*)d_in[1];
  const float* ln_b  = (const float*)d_in[2];
  const float* Wu    = (const float*)d_in[3];
  const float* bu    = (const float*)d_in[4];
  const float* Wv    = (const float*)d_in[5];
  const float* bv    = (const float*)d_in[6];
  const float* Wbase = (const float*)d_in[7];
  const float* bbase = (const float*)d_in[8];
  const float* q_w   = (const float*)d_in[9];
  const float* q_b   = (const float*)d_in[10];
  const float* k_w   = (const float*)d_in[11];
  const float* k_b   = (const float*)d_in[12];
  const float* w_rel = (const float*)d_in[13];
  const float* Wo    = (const float*)d_in[14];
  const float* bo    = (const float*)d_in[15];
  float* out = (float*)d_out;

  char* ws = (char*)d_ws;
  ushort* X    = (ushort*)(ws);                     // 8192*256  (4 MB); reused as WREP after gemms
  ushort* U    = (ushort*)(ws + (4u  << 20));       // 8192*512  (8 MB)
  ushort* VT   = (ushort*)(ws + (12u << 20));       // 512*8192  (8 MB)
  ushort* BASE = (ushort*)(ws + (20u << 20));       // 8192*128  (2 MB)
  ushort* Qb   = (ushort*)(ws + (22u << 20));       // 2 MB
  ushort* Kb   = (ushort*)(ws + (24u << 20));       // 2 MB
  ushort* KVU  = (ushort*)(ws + (26u << 20));       // 8 MB
  ushort* WUT  = (ushort*)(ws + (34u << 20));
  ushort* WVT  = (ushort*)(ws + (34u << 20) + 512*256*2);
  ushort* WBT  = (ushort*)(ws + (34u << 20) + 2*512*256*2);
  ushort* WOT  = (ushort*)(ws + (34u << 20) + 2*512*256*2 + 128*256*2);
  float*  WREP = (float*)(ws);                      // 128 KB, written after X is dead

  ln_kernel<<<2048, 256, 0, stream>>>(query, ln_w, ln_b, X);
  wt_kernel<<<(512*256 + 255) / 256, 256, 0, stream>>>(Wu, WUT, 256, 512);
  wt_kernel<<<(512*256 + 255) / 256, 256, 0, stream>>>(Wv, WVT, 256, 512);
  wt_kernel<<<(128*256 + 255) / 256, 256, 0, stream>>>(Wbase, WBT, 256, 128);
  wt_kernel<<<(512*256 + 255) / 256, 256, 0, stream>>>(Wo, WOT, 512, 256);
  gemm_kernel<0><<<dim3(64, 8), 256, 0, stream>>>(X, WUT, bu, U, 8192, 512, 256);
  gemm_kernel<2><<<dim3(64, 8), 256, 0, stream>>>(X, WVT, bv, VT, 8192, 512, 256);
  gemm_kernel<0><<<dim3(64, 2), 256, 0, stream>>>(X, WBT, bbase, BASE, 8192, 128, 256);
  wrep_kernel<<<128, 256, 0, stream>>>(w_rel, WREP);   // X dead from here
  rope_kernel<<<2048, 256, 0, stream>>>(BASE, q_w, q_b, k_w, k_b, Qb, Kb);
  attn_kernel<<<dim3(32, 4, 2), 512, 0, stream>>>(Qb, Kb, VT, U, WREP, KVU);
  gemm_kernel<1><<<dim3(64, 4), 256, 0, stream>>>(KVU, WOT, bo, out, 8192, 256, 512);
}

// Round 9
// 203.959 us; speedup vs baseline: 1.4242x; 1.4242x over previous
//
#include <hip/hip_runtime.h>
#include <hip/hip_bf16.h>
#include <math.h>

typedef __bf16 bf16_8 __attribute__((ext_vector_type(8)));
typedef float f32x4 __attribute__((ext_vector_type(4)));
typedef float f32x16 __attribute__((ext_vector_type(16)));

#define D_ 256
#define S_ 128
#define E_ 512
#define MPE_ 4096
#define B_ 2
#define N_ 4096
#define M_TOT (B_*N_)   // 8192

__device__ __forceinline__ ushort f2b(float f) {
  union { float f; uint u; } x; x.f = f;
  uint r = (x.u + 0x7FFFu + ((x.u >> 16) & 1u)) >> 16;
  return (ushort)r;
}
__device__ __forceinline__ float b2f(ushort b) {
  union { uint u; float f; } x; x.u = ((uint)b) << 16;
  return x.f;
}

__device__ __forceinline__ void gl_lds16(const void* g, void* l) {
  __builtin_amdgcn_global_load_lds(
      (const __attribute__((address_space(1))) void*)g,
      (__attribute__((address_space(3))) void*)l, 16, 0, 0);
}

// ---------------- LayerNorm: one wave per row ----------------
__global__ __launch_bounds__(256) void ln_kernel(const float* __restrict__ q,
    const float* __restrict__ w, const float* __restrict__ b,
    ushort* __restrict__ x) {
  int wid = threadIdx.x >> 6, lane = threadIdx.x & 63;
  int row = blockIdx.x * 4 + wid;
  const float* qr = q + (size_t)row * D_;
  float4 v = *(const float4*)(qr + lane * 4);
  float s  = v.x + v.y + v.z + v.w;
  float ss = v.x*v.x + v.y*v.y + v.z*v.z + v.w*v.w;
  #pragma unroll
  for (int off = 32; off; off >>= 1) {
    s  += __shfl_xor(s, off);
    ss += __shfl_xor(ss, off);
  }
  float mu   = s * (1.0f / 256.0f);
  float var  = ss * (1.0f / 256.0f) - mu * mu;
  float rstd = rsqrtf(var + 1e-5f);
  ushort4 o;
  float vv[4] = {v.x, v.y, v.z, v.w};
  ushort ot[4];
  #pragma unroll
  for (int j = 0; j < 4; ++j) {
    int c = lane * 4 + j;
    ot[j] = f2b((vv[j] - mu) * rstd * w[c] + b[c]);
  }
  o.x = ot[0]; o.y = ot[1]; o.z = ot[2]; o.w = ot[3];
  *(ushort4*)(x + (size_t)row * D_ + lane * 4) = o;
}

// ---------------- weight transpose + cast ----------------
__global__ void wt_kernel(const float* __restrict__ in, ushort* __restrict__ out,
                          int R, int C) {
  int o = blockIdx.x * 256 + threadIdx.x;
  if (o >= R * C) return;
  int c = o / R, r = o - c * R;
  out[o] = f2b(in[r * C + c]);
}

// ---------------- bias replicate: wrep[c][i] = w_rel[min(i+c,8190)], c=0..3 ----------------
__global__ __launch_bounds__(256) void wrep_kernel(const float* __restrict__ w_rel,
                                                   float* __restrict__ wrep) {
  int idx = blockIdx.x * 256 + threadIdx.x;   // 0..32767
  int c = idx >> 13, i = idx & 8191;
  int s = i + c; if (s > 8190) s = 8190;
  wrep[idx] = w_rel[s];
}

// ---------------- GEMM: A[M][K] bf16, Bt[N][K] bf16, tile 128x64, BK=64 ----------------
template<int EPI>
__global__ __launch_bounds__(256) void gemm_kernel(
    const ushort* __restrict__ A, const ushort* __restrict__ Bt,
    const float* __restrict__ bias, void* __restrict__ out,
    int M, int N, int K) {
  __shared__ alignas(16) ushort As[128 * 64];
  __shared__ alignas(16) ushort Bs[64 * 64];
  int tid = threadIdx.x;
  int lane = tid & 63, wid = tid >> 6;
  int m0 = blockIdx.x * 128, n0 = blockIdx.y * 64;
  int r16 = lane & 15, kq = lane >> 4;
  f32x4 acc[2][4] = {};
  for (int k0 = 0; k0 < K; k0 += 64) {
    __syncthreads();
    #pragma unroll
    for (int t = 0; t < 4; ++t) {
      int cid = tid + t * 256;
      int row = cid >> 3, c = cid & 7;
      uint4 d = *(const uint4*)(A + ((size_t)(m0 + row) * K + k0 + c * 8));
      *(uint4*)&As[row * 64 + ((c ^ (row & 7)) * 8)] = d;
    }
    #pragma unroll
    for (int t = 0; t < 2; ++t) {
      int cid = tid + t * 256;
      int row = cid >> 3, c = cid & 7;
      uint4 d = *(const uint4*)(Bt + ((size_t)(n0 + row) * K + k0 + c * 8));
      *(uint4*)&Bs[row * 64 + ((c ^ (row & 7)) * 8)] = d;
    }
    __syncthreads();
    #pragma unroll
    for (int ks = 0; ks < 2; ++ks) {
      bf16_8 af[2], bfr[4];
      int c = ks * 4 + kq;
      #pragma unroll
      for (int fm = 0; fm < 2; ++fm) {
        int r = wid * 32 + fm * 16 + r16;
        af[fm] = *(const bf16_8*)&As[r * 64 + ((c ^ (r & 7)) * 8)];
      }
      #pragma unroll
      for (int fn = 0; fn < 4; ++fn) {
        int r = fn * 16 + r16;
        bfr[fn] = *(const bf16_8*)&Bs[r * 64 + ((c ^ (r & 7)) * 8)];
      }
      #pragma unroll
      for (int fm = 0; fm < 2; ++fm)
        #pragma unroll
        for (int fn = 0; fn < 4; ++fn)
          acc[fm][fn] = __builtin_amdgcn_mfma_f32_16x16x32_bf16(af[fm], bfr[fn], acc[fm][fn], 0, 0, 0);
    }
  }
  #pragma unroll
  for (int fm = 0; fm < 2; ++fm)
    #pragma unroll
    for (int fn = 0; fn < 4; ++fn)
      #pragma unroll
      for (int reg = 0; reg < 4; ++reg) {
        int ml = wid * 32 + fm * 16 + kq * 4 + reg;
        int nl = fn * 16 + r16;
        size_t gm = m0 + ml, gn = n0 + nl;
        float val = acc[fm][fn][reg] + bias[gn];
        if (EPI == 0) {
          float y = val / (1.0f + expf(-val));
          ((ushort*)out)[gm * N + gn] = f2b(y);
        } else if (EPI == 2) {
          float y = val / (1.0f + expf(-val));
          ((ushort*)out)[gn * (size_t)M_TOT + gm] = f2b(y);
        } else {
          ((float*)out)[gm * N + gn] = val;
        }
      }
}

// ---------------- RoPE (outputs pre-scaled by 1/64 so q.k carries 1/MPE) ----------------
__global__ __launch_bounds__(256) void rope_kernel(const ushort* __restrict__ base,
    const float* __restrict__ qw, const float* __restrict__ qb,
    const float* __restrict__ kw, const float* __restrict__ kb,
    ushort* __restrict__ Q, ushort* __restrict__ Kk) {
  int g = blockIdx.x * 256 + threadIdx.x;
  int row = g >> 6, i = g & 63;
  int n = row & (N_ - 1);
  float invf = powf(10000.0f, -(float)i * (1.0f / 64.0f));
  float sv, cv;
  sincosf((float)n * invf, &sv, &cv);
  const float sc = 0.015625f;   // 1/64; (1/64)^2 = 1/4096 = 1/MPE
  float b1 = b2f(base[row * S_ + i]), b2 = b2f(base[row * S_ + 64 + i]);
  float x1q = b1 * qw[i] + qb[i], x2q = b2 * qw[64 + i] + qb[64 + i];
  Q[row * S_ + i]      = f2b((x1q * cv - x2q * sv) * sc);
  Q[row * S_ + 64 + i] = f2b((x2q * cv + x1q * sv) * sc);
  float x1k = b1 * kw[i] + kb[i], x2k = b2 * kw[64 + i] + kb[64 + i];
  Kk[row * S_ + i]      = f2b((x1k * cv - x2k * sv) * sc);
  Kk[row * S_ + 64 + i] = f2b((x2k * cv + x1k * sv) * sc);
}

// ---------------- fused attention: 32x32 MFMA, P in-register via permlane ----------------
// grid (32 m-tiles of 128, 4 e-chunks of 128, 2 b) = 256 blocks, 256 thr (4 waves),
// 2 blocks/CU (64KB LDS each). Wave = 32 m-rows. Swapped QK: mfma(A=K,B=Q) ->
// lane col = m, rows = n. Transform + cvt_pk + permlane32_swap builds PV A-frags
// entirely in registers (NO P LDS, no mid-iter cross-wave dependency).
// K,V double-buffered LDS via global_load_lds. One barrier/iter.
__global__ __launch_bounds__(256, 2) void attn_kernel(
    const ushort* __restrict__ Q, const ushort* __restrict__ Kd,
    const ushort* __restrict__ VT, const ushort* __restrict__ U,
    const float* __restrict__ wrep, ushort* __restrict__ KVU) {
  __shared__ alignas(16) ushort Ks[2][64 * 128];   // 32 KB
  __shared__ alignas(16) ushort Vs[2][128 * 64];   // 32 KB
  const int tid = threadIdx.x, lane = tid & 63, wv = tid >> 6;
  const int b = blockIdx.z, m0 = blockIdx.x * 128, e0 = blockIdx.y * 128;
  const int l31 = lane & 31, hi = lane >> 5;
  const int mrow = m0 + wv * 32 + l31;             // this lane's m (= output col)

  // bias: idx(t,tile,rg) = 4095 + 64t + 32tile + 8rg + 4hi - mrow  (always in [0,8190])
  const int bbase = 4095 + 4 * hi - mrow;
  const int csel = bbase & 3;
  const float* wrow = wrep + csel * 8192 + (bbase - csel);

  // Q fragments (B-operand: col=m=l31, k = 16ks + 8hi + j)
  bf16_8 qf[8];
  #pragma unroll
  for (int ks = 0; ks < 8; ++ks)
    qf[ks] = *(const bf16_8*)(Q + ((size_t)(b * N_ + mrow) * S_ + ks * 16 + hi * 8));

  auto stage_k = [&](int bi, int nt) {
    int n0s = nt * 64;
    #pragma unroll
    for (int tt = 0; tt < 4; ++tt) {           // 64n x 128k = 1024 chunks
      int p = tt * 256 + tid;
      int row = p >> 4, sc2 = p & 15;
      int cc = sc2 ^ (row & 7);
      gl_lds16(Kd + ((size_t)(b * N_ + n0s + row) * S_ + cc * 8),
               &Ks[bi][(tt * 256 + wv * 64) * 8]);
    }
  };
  auto stage_v = [&](int bi, int nt) {
    int n0s = nt * 64;
    #pragma unroll
    for (int tt = 0; tt < 4; ++tt) {           // 128e x 64n = 1024 chunks
      int p = tt * 256 + tid;
      int er = p >> 3, sc2 = p & 7;
      int nc = sc2 ^ (er & 7);
      gl_lds16(VT + ((size_t)(e0 + er) * M_TOT + b * N_ + n0s + nc * 8),
               &Vs[bi][(tt * 256 + wv * 64) * 8]);
    }
  };

  f32x16 acc[4] = {};
  uint4 paA[4], paB[4];

  auto body = [&](int t, int cur, uint4 (&paW)[4], uint4 (&paR)[4],
                  bool doPV, bool doK) {
    // ---- bias float4 loads (early issue) ----
    float4 bb[8];
    #pragma unroll
    for (int tile = 0; tile < 2; ++tile)
      #pragma unroll
      for (int rg = 0; rg < 4; ++rg)
        bb[tile * 4 + rg] = *(const float4*)(wrow + 64 * t + 32 * tile + 8 * rg);
    // ---- stage K(t+1), V(t) ----
    if (doK) stage_k(cur ^ 1, t + 1);
    stage_v(cur, t);
    __builtin_amdgcn_sched_barrier(0);
    // ---- QK: s{0,1} = mfma32(K-frag, Q-frag): col=m, rows=n ----
    const char* ksb = (const char*)&Ks[cur][0];
    f32x16 s0 = {}, s1 = {};
    __builtin_amdgcn_s_setprio(1);
    #pragma unroll
    for (int ks = 0; ks < 8; ++ks) {
      int slot = (2 * ks + hi) ^ (l31 & 7);    // (row&7) same for both n-tiles
      bf16_8 kf0 = *(const bf16_8*)(ksb + l31 * 256 + slot * 16);
      s0 = __builtin_amdgcn_mfma_f32_32x32x16_bf16(kf0, qf[ks], s0, 0, 0, 0);
      bf16_8 kf1 = *(const bf16_8*)(ksb + (32 + l31) * 256 + slot * 16);
      s1 = __builtin_amdgcn_mfma_f32_32x32x16_bf16(kf1, qf[ks], s1, 0, 0, 0);
    }
    __builtin_amdgcn_s_setprio(0);
    // ---- PV(t-1): A = paR (in-reg), B = V-frags from Vs[cur^1] ----
    if (doPV) {
      const char* vsb = (const char*)&Vs[cur ^ 1][0];
      __builtin_amdgcn_s_setprio(1);
      #pragma unroll
      for (int kb = 0; kb < 4; ++kb) {
        bf16_8 pa = *(const bf16_8*)&paR[kb];
        #pragma unroll
        for (int et = 0; et < 4; ++et) {
          int e = et * 32 + l31;
          int slot = (2 * kb + hi) ^ (e & 7);
          bf16_8 vf = *(const bf16_8*)(vsb + e * 128 + slot * 16);
          acc[et] = __builtin_amdgcn_mfma_f32_32x32x16_bf16(pa, vf, acc[et], 0, 0, 0);
        }
      }
      __builtin_amdgcn_s_setprio(0);
    }
    // ---- transform: relu(s+bias)^2 -> bf16 packed -> permlane -> paW ----
    uint w0[2][4], w1[2][4];
    #pragma unroll
    for (int tile = 0; tile < 2; ++tile)
      #pragma unroll
      for (int rg = 0; rg < 4; ++rg) {
        float4 b4 = bb[tile * 4 + rg];
        float v0, v1, v2, v3;
        if (tile == 0) {
          v0 = s0[4*rg+0]; v1 = s0[4*rg+1]; v2 = s0[4*rg+2]; v3 = s0[4*rg+3];
        } else {
          v0 = s1[4*rg+0]; v1 = s1[4*rg+1]; v2 = s1[4*rg+2]; v3 = s1[4*rg+3];
        }
        float t0 = fmaxf(v0 + b4.x, 0.f); t0 *= t0;
        float t1 = fmaxf(v1 + b4.y, 0.f); t1 *= t1;
        float t2 = fmaxf(v2 + b4.z, 0.f); t2 *= t2;
        float t3 = fmaxf(v3 + b4.w, 0.f); t3 *= t3;
        uint p01, p23;
        asm("v_cvt_pk_bf16_f32 %0, %1, %2" : "=v"(p01) : "v"(t0), "v"(t1));
        asm("v_cvt_pk_bf16_f32 %0, %1, %2" : "=v"(p23) : "v"(t2), "v"(t3));
        w0[tile][rg] = p01;
        w1[tile][rg] = p23;
      }
    #pragma unroll
    for (int kb = 0; kb < 4; ++kb) {
      int ts = kb >> 1, rs = 2 * (kb & 1);
      uint x0 = w0[ts][rs], y0 = w0[ts][rs + 1];
      asm("v_permlane32_swap_b32 %0, %1" : "+v"(x0), "+v"(y0));
      uint x1 = w1[ts][rs], y1 = w1[ts][rs + 1];
      asm("v_permlane32_swap_b32 %0, %1" : "+v"(x1), "+v"(y1));
      uint4 pk; pk.x = x0; pk.y = x1; pk.z = y0; pk.w = y1;
      paW[kb] = pk;
    }
    asm volatile("s_waitcnt vmcnt(0) lgkmcnt(0)" ::: "memory");
    __builtin_amdgcn_s_barrier();
  };

  // prologue: K(0)
  stage_k(0, 0);
  asm volatile("s_waitcnt vmcnt(0) lgkmcnt(0)" ::: "memory");
  __builtin_amdgcn_s_barrier();

  body(0, 0, paA, paB, false, true);
  for (int t2 = 0; t2 < 31; ++t2) {
    body(2 * t2 + 1, 1, paB, paA, true, true);
    body(2 * t2 + 2, 0, paA, paB, true, true);
  }
  body(63, 1, paB, paA, true, false);

  // drain: PV(63) from Vs[1], paB
  {
    const char* vsb = (const char*)&Vs[1][0];
    #pragma unroll
    for (int kb = 0; kb < 4; ++kb) {
      bf16_8 pa = *(const bf16_8*)&paB[kb];
      #pragma unroll
      for (int et = 0; et < 4; ++et) {
        int e = et * 32 + l31;
        int slot = (2 * kb + hi) ^ (e & 7);
        bf16_8 vf = *(const bf16_8*)(vsb + e * 128 + slot * 16);
        acc[et] = __builtin_amdgcn_mfma_f32_32x32x16_bf16(pa, vf, acc[et], 0, 0, 0);
      }
    }
  }

  // ---- epilogue: KVU = bf16(u * acc); D: col=e(l31), row m = (reg&3)+8(reg>>2)+4hi ----
  #pragma unroll
  for (int et = 0; et < 4; ++et)
    #pragma unroll
    for (int reg = 0; reg < 16; ++reg) {
      int ml = (reg & 3) + 8 * (reg >> 2) + 4 * hi;
      size_t grow = (size_t)b * N_ + m0 + wv * 32 + ml;
      size_t ge = e0 + et * 32 + l31;
      float uu = b2f(U[grow * E_ + ge]);
      KVU[grow * E_ + ge] = f2b(uu * acc[et][reg]);
    }
}

extern "C" void kernel_launch(void* const* d_in, const int* in_sizes, int n_in,
                              void* d_out, int out_size, void* d_ws, size_t ws_size,
                              hipStream_t stream) {
  const float* query = (const float*)d_in[0];
  const float* ln_w  = (const float*)d_in[1];
  const float* ln_b  = (const float*)d_in[2];
  const float* Wu    = (const float*)d_in[3];
  const float* bu    = (const float*)d_in[4];
  const float* Wv    = (const float*)d_in[5];
  const float* bv    = (const float*)d_in[6];
  const float* Wbase = (const float*)d_in[7];
  const float* bbase = (const float*)d_in[8];
  const float* q_w   = (const float*)d_in[9];
  const float* q_b   = (const float*)d_in[10];
  const float* k_w   = (const float*)d_in[11];
  const float* k_b   = (const float*)d_in[12];
  const float* w_rel = (const float*)d_in[13];
  const float* Wo    = (const float*)d_in[14];
  const float* bo    = (const float*)d_in[15];
  float* out = (float*)d_out;

  char* ws = (char*)d_ws;
  ushort* X    = (ushort*)(ws);                     // 8192*256  (4 MB); reused as WREP after gemms
  ushort* U    = (ushort*)(ws + (4u  << 20));       // 8192*512  (8 MB)
  ushort* VT   = (ushort*)(ws + (12u << 20));       // 512*8192  (8 MB)
  ushort* BASE = (ushort*)(ws + (20u << 20));       // 8192*128  (2 MB)
  ushort* Qb   = (ushort*)(ws + (22u << 20));       // 2 MB
  ushort* Kb   = (ushort*)(ws + (24u << 20));       // 2 MB
  ushort* KVU  = (ushort*)(ws + (26u << 20));       // 8 MB
  ushort* WUT  = (ushort*)(ws + (34u << 20));
  ushort* WVT  = (ushort*)(ws + (34u << 20) + 512*256*2);
  ushort* WBT  = (ushort*)(ws + (34u << 20) + 2*512*256*2);
  ushort* WOT  = (ushort*)(ws + (34u << 20) + 2*512*256*2 + 128*256*2);
  float*  WREP = (float*)(ws);                      // 128 KB, written after X is dead

  ln_kernel<<<2048, 256, 0, stream>>>(query, ln_w, ln_b, X);
  wt_kernel<<<(512*256 + 255) / 256, 256, 0, stream>>>(Wu, WUT, 256, 512);
  wt_kernel<<<(512*256 + 255) / 256, 256, 0, stream>>>(Wv, WVT, 256, 512);
  wt_kernel<<<(128*256 + 255) / 256, 256, 0, stream>>>(Wbase, WBT, 256, 128);
  wt_kernel<<<(512*256 + 255) / 256, 256, 0, stream>>>(Wo, WOT, 512, 256);
  gemm_kernel<0><<<dim3(64, 8), 256, 0, stream>>>(X, WUT, bu, U, 8192, 512, 256);
  gemm_kernel<2><<<dim3(64, 8), 256, 0, stream>>>(X, WVT, bv, VT, 8192, 512, 256);
  gemm_kernel<0><<<dim3(64, 2), 256, 0, stream>>>(X, WBT, bbase, BASE, 8192, 128, 256);
  wrep_kernel<<<128, 256, 0, stream>>>(w_rel, WREP);   // X dead from here
  rope_kernel<<<2048, 256, 0, stream>>>(BASE, q_w, q_b, k_w, k_b, Qb, Kb);
  attn_kernel<<<dim3(32, 4, 2), 256, 0, stream>>>(Qb, Kb, VT, U, WREP, KVU);
  gemm_kernel<1><<<dim3(64, 4), 256, 0, stream>>>(KVU, WOT, bo, out, 8192, 256, 512);
}

// Round 10
// 171.226 us; speedup vs baseline: 1.6965x; 1.1912x over previous
//
#include <hip/hip_runtime.h>
#include <hip/hip_bf16.h>
#include <math.h>

typedef __bf16 bf16_8 __attribute__((ext_vector_type(8)));
typedef float f32x4 __attribute__((ext_vector_type(4)));
typedef float f32x16 __attribute__((ext_vector_type(16)));

#define D_ 256
#define S_ 128
#define E_ 512
#define MPE_ 4096
#define B_ 2
#define N_ 4096
#define M_TOT (B_*N_)   // 8192

__device__ __forceinline__ ushort f2b(float f) {
  union { float f; uint u; } x; x.f = f;
  uint r = (x.u + 0x7FFFu + ((x.u >> 16) & 1u)) >> 16;
  return (ushort)r;
}
__device__ __forceinline__ float b2f(ushort b) {
  union { uint u; float f; } x; x.u = ((uint)b) << 16;
  return x.f;
}

__device__ __forceinline__ void gl_lds16(const void* g, void* l) {
  __builtin_amdgcn_global_load_lds(
      (const __attribute__((address_space(1))) void*)g,
      (__attribute__((address_space(3))) void*)l, 16, 0, 0);
}

// ---------------- LayerNorm: one wave per row ----------------
__global__ __launch_bounds__(256) void ln_kernel(const float* __restrict__ q,
    const float* __restrict__ w, const float* __restrict__ b,
    ushort* __restrict__ x) {
  int wid = threadIdx.x >> 6, lane = threadIdx.x & 63;
  int row = blockIdx.x * 4 + wid;
  const float* qr = q + (size_t)row * D_;
  float4 v = *(const float4*)(qr + lane * 4);
  float s  = v.x + v.y + v.z + v.w;
  float ss = v.x*v.x + v.y*v.y + v.z*v.z + v.w*v.w;
  #pragma unroll
  for (int off = 32; off; off >>= 1) {
    s  += __shfl_xor(s, off);
    ss += __shfl_xor(ss, off);
  }
  float mu   = s * (1.0f / 256.0f);
  float var  = ss * (1.0f / 256.0f) - mu * mu;
  float rstd = rsqrtf(var + 1e-5f);
  ushort4 o;
  float vv[4] = {v.x, v.y, v.z, v.w};
  ushort ot[4];
  #pragma unroll
  for (int j = 0; j < 4; ++j) {
    int c = lane * 4 + j;
    ot[j] = f2b((vv[j] - mu) * rstd * w[c] + b[c]);
  }
  o.x = ot[0]; o.y = ot[1]; o.z = ot[2]; o.w = ot[3];
  *(ushort4*)(x + (size_t)row * D_ + lane * 4) = o;
}

// ---------------- weight transpose + cast ----------------
__global__ void wt_kernel(const float* __restrict__ in, ushort* __restrict__ out,
                          int R, int C) {
  int o = blockIdx.x * 256 + threadIdx.x;
  if (o >= R * C) return;
  int c = o / R, r = o - c * R;
  out[o] = f2b(in[r * C + c]);
}

// ---------------- bias replicate: wrep[c][i] = w_rel[min(i+c,8190)], c=0..3 ----------------
__global__ __launch_bounds__(256) void wrep_kernel(const float* __restrict__ w_rel,
                                                   float* __restrict__ wrep) {
  int idx = blockIdx.x * 256 + threadIdx.x;   // 0..32767
  int c = idx >> 13, i = idx & 8191;
  int s = i + c; if (s > 8190) s = 8190;
  wrep[idx] = w_rel[s];
}

// ---------------- GEMM: A[M][K] bf16, Bt[N][K] bf16, tile 128x64, BK=64 ----------------
template<int EPI>
__global__ __launch_bounds__(256) void gemm_kernel(
    const ushort* __restrict__ A, const ushort* __restrict__ Bt,
    const float* __restrict__ bias, void* __restrict__ out,
    int M, int N, int K) {
  __shared__ alignas(16) ushort As[128 * 64];
  __shared__ alignas(16) ushort Bs[64 * 64];
  int tid = threadIdx.x;
  int lane = tid & 63, wid = tid >> 6;
  int m0 = blockIdx.x * 128, n0 = blockIdx.y * 64;
  int r16 = lane & 15, kq = lane >> 4;
  f32x4 acc[2][4] = {};
  for (int k0 = 0; k0 < K; k0 += 64) {
    __syncthreads();
    #pragma unroll
    for (int t = 0; t < 4; ++t) {
      int cid = tid + t * 256;
      int row = cid >> 3, c = cid & 7;
      uint4 d = *(const uint4*)(A + ((size_t)(m0 + row) * K + k0 + c * 8));
      *(uint4*)&As[row * 64 + ((c ^ (row & 7)) * 8)] = d;
    }
    #pragma unroll
    for (int t = 0; t < 2; ++t) {
      int cid = tid + t * 256;
      int row = cid >> 3, c = cid & 7;
      uint4 d = *(const uint4*)(Bt + ((size_t)(n0 + row) * K + k0 + c * 8));
      *(uint4*)&Bs[row * 64 + ((c ^ (row & 7)) * 8)] = d;
    }
    __syncthreads();
    #pragma unroll
    for (int ks = 0; ks < 2; ++ks) {
      bf16_8 af[2], bfr[4];
      int c = ks * 4 + kq;
      #pragma unroll
      for (int fm = 0; fm < 2; ++fm) {
        int r = wid * 32 + fm * 16 + r16;
        af[fm] = *(const bf16_8*)&As[r * 64 + ((c ^ (r & 7)) * 8)];
      }
      #pragma unroll
      for (int fn = 0; fn < 4; ++fn) {
        int r = fn * 16 + r16;
        bfr[fn] = *(const bf16_8*)&Bs[r * 64 + ((c ^ (r & 7)) * 8)];
      }
      #pragma unroll
      for (int fm = 0; fm < 2; ++fm)
        #pragma unroll
        for (int fn = 0; fn < 4; ++fn)
          acc[fm][fn] = __builtin_amdgcn_mfma_f32_16x16x32_bf16(af[fm], bfr[fn], acc[fm][fn], 0, 0, 0);
    }
  }
  #pragma unroll
  for (int fm = 0; fm < 2; ++fm)
    #pragma unroll
    for (int fn = 0; fn < 4; ++fn)
      #pragma unroll
      for (int reg = 0; reg < 4; ++reg) {
        int ml = wid * 32 + fm * 16 + kq * 4 + reg;
        int nl = fn * 16 + r16;
        size_t gm = m0 + ml, gn = n0 + nl;
        float val = acc[fm][fn][reg] + bias[gn];
        if (EPI == 0) {
          float y = val / (1.0f + expf(-val));
          ((ushort*)out)[gm * N + gn] = f2b(y);
        } else if (EPI == 2) {
          float y = val / (1.0f + expf(-val));
          ((ushort*)out)[gn * (size_t)M_TOT + gm] = f2b(y);
        } else {
          ((float*)out)[gm * N + gn] = val;
        }
      }
}

// ---------------- RoPE (outputs pre-scaled by 1/64 so q.k carries 1/MPE) ----------------
__global__ __launch_bounds__(256) void rope_kernel(const ushort* __restrict__ base,
    const float* __restrict__ qw, const float* __restrict__ qb,
    const float* __restrict__ kw, const float* __restrict__ kb,
    ushort* __restrict__ Q, ushort* __restrict__ Kk) {
  int g = blockIdx.x * 256 + threadIdx.x;
  int row = g >> 6, i = g & 63;
  int n = row & (N_ - 1);
  float invf = powf(10000.0f, -(float)i * (1.0f / 64.0f));
  float sv, cv;
  sincosf((float)n * invf, &sv, &cv);
  const float sc = 0.015625f;   // 1/64; (1/64)^2 = 1/4096 = 1/MPE
  float b1 = b2f(base[row * S_ + i]), b2 = b2f(base[row * S_ + 64 + i]);
  float x1q = b1 * qw[i] + qb[i], x2q = b2 * qw[64 + i] + qb[64 + i];
  Q[row * S_ + i]      = f2b((x1q * cv - x2q * sv) * sc);
  Q[row * S_ + 64 + i] = f2b((x2q * cv + x1q * sv) * sc);
  float x1k = b1 * kw[i] + kb[i], x2k = b2 * kw[64 + i] + kb[64 + i];
  Kk[row * S_ + i]      = f2b((x1k * cv - x2k * sv) * sc);
  Kk[row * S_ + 64 + i] = f2b((x2k * cv + x1k * sv) * sc);
}

// ---------------- fused attention: 32x32 MFMA, in-reg P, 8 waves (4m x 2nh) ----------------
// grid (32 m-tiles of 128, 4 e-chunks of 128, 2 b) = 256 blocks, 512 thr (8 waves),
// 2 waves/SIMD. Wave = 32 m-rows x 32 n-half. QK: 8 mfma32 (no duplication);
// PV over own n-half: 8 mfma32, acc reduced across n-half pairs once at the end
// through LDS. P in registers via cvt_pk + permlane32_swap. One barrier/iter.
__global__ __launch_bounds__(512, 2) void attn_kernel(
    const ushort* __restrict__ Q, const ushort* __restrict__ Kd,
    const ushort* __restrict__ VT, const ushort* __restrict__ U,
    const float* __restrict__ wrep, ushort* __restrict__ KVU) {
  __shared__ alignas(16) ushort SM[32768];   // 64 KB: K[2]=2x16KB @0, V[2]=2x16KB @32KB
  char* SMc = (char*)&SM[0];
  const int tid = threadIdx.x, lane = tid & 63, wid = tid >> 6;
  const int wg = wid >> 1, nh = wid & 1;
  const int b = blockIdx.z, m0 = blockIdx.x * 128, e0 = blockIdx.y * 128;
  const int l31 = lane & 31, hi = lane >> 5;
  const int mrow = m0 + wg * 32 + l31;             // lane's m (= output col in QK)

  // bias: idx = 4095 + (64t + 32nh + 8rg + (reg&3) + 4hi) - mrow, always in [0,8190]
  const int bbase = 4095 + 32 * nh + 4 * hi - mrow;
  const int csel = bbase & 3;
  const float* wrow = wrep + csel * 8192 + (bbase - csel);

  // Q fragments (B-operand: col=m=l31, k = 16ks + 8hi + j)
  bf16_8 qf[8];
  #pragma unroll
  for (int ks = 0; ks < 8; ++ks)
    qf[ks] = *(const bf16_8*)(Q + ((size_t)(b * N_ + mrow) * S_ + ks * 16 + hi * 8));

  auto stage_k = [&](int bi, int nt) {
    int n0s = nt * 64;
    #pragma unroll
    for (int tt = 0; tt < 2; ++tt) {           // 64n x 128k = 1024 chunks / 512 thr
      int p = tt * 512 + tid;
      int row = p >> 4, sc2 = p & 15;
      int cc = sc2 ^ (row & 7);
      gl_lds16(Kd + ((size_t)(b * N_ + n0s + row) * S_ + cc * 8),
               SMc + bi * 16384 + (tt * 512 + wid * 64) * 16);
    }
  };
  auto stage_v = [&](int bi, int nt) {
    int n0s = nt * 64;
    #pragma unroll
    for (int tt = 0; tt < 2; ++tt) {           // 128e x 64n = 1024 chunks
      int p = tt * 512 + tid;
      int er = p >> 3, sc2 = p & 7;
      int nc = sc2 ^ (er & 7);
      gl_lds16(VT + ((size_t)(e0 + er) * M_TOT + b * N_ + n0s + nc * 8),
               SMc + 32768 + bi * 16384 + (tt * 512 + wid * 64) * 16);
    }
  };

  f32x16 acc[4] = {};
  uint4 paA[2], paB[2];

  auto do_pv = [&](int vb, const uint4 (&paR)[2]) {
    const char* vsb = SMc + 32768 + vb * 16384;
    __builtin_amdgcn_s_setprio(1);
    #pragma unroll
    for (int kb = 0; kb < 2; ++kb) {
      bf16_8 pa = *(const bf16_8*)&paR[kb];
      #pragma unroll
      for (int et = 0; et < 4; ++et) {
        int e = et * 32 + l31;
        int slot = (4 * nh + 2 * kb + hi) ^ (e & 7);
        bf16_8 vf = *(const bf16_8*)(vsb + e * 128 + slot * 16);
        acc[et] = __builtin_amdgcn_mfma_f32_32x32x16_bf16(pa, vf, acc[et], 0, 0, 0);
      }
    }
    __builtin_amdgcn_s_setprio(0);
  };

  auto body = [&](int t, int cur, uint4 (&paW)[2], const uint4 (&paR)[2],
                  bool doPV, bool doK) {
    // ---- bias float4 loads (early issue) ----
    float4 bb[4];
    #pragma unroll
    for (int rg = 0; rg < 4; ++rg)
      bb[rg] = *(const float4*)(wrow + 64 * t + 8 * rg);
    // ---- stage K(t+1), V(t) ----
    if (doK) stage_k(cur ^ 1, t + 1);
    stage_v(cur, t);
    __builtin_amdgcn_sched_barrier(0);
    // ---- QK: s0 = mfma32(K-frag, Q-frag): col=m, rows = own 32 n ----
    const char* ksb = SMc + cur * 16384;
    f32x16 s0 = {};
    __builtin_amdgcn_s_setprio(1);
    #pragma unroll
    for (int ks = 0; ks < 8; ++ks) {
      int row = nh * 32 + l31;
      int slot = (2 * ks + hi) ^ (l31 & 7);
      bf16_8 kf = *(const bf16_8*)(ksb + row * 256 + slot * 16);
      s0 = __builtin_amdgcn_mfma_f32_32x32x16_bf16(kf, qf[ks], s0, 0, 0, 0);
    }
    __builtin_amdgcn_s_setprio(0);
    // ---- PV(t-1): in-reg P (paR), V from buffer cur^1 ----
    if (doPV) do_pv(cur ^ 1, paR);
    // ---- transform: relu(s+bias)^2 -> bf16 -> permlane -> paW ----
    uint w0[4], w1[4];
    #pragma unroll
    for (int rg = 0; rg < 4; ++rg) {
      float4 b4 = bb[rg];
      float t0 = fmaxf(s0[4*rg+0] + b4.x, 0.f); t0 *= t0;
      float t1 = fmaxf(s0[4*rg+1] + b4.y, 0.f); t1 *= t1;
      float t2 = fmaxf(s0[4*rg+2] + b4.z, 0.f); t2 *= t2;
      float t3 = fmaxf(s0[4*rg+3] + b4.w, 0.f); t3 *= t3;
      asm("v_cvt_pk_bf16_f32 %0, %1, %2" : "=v"(w0[rg]) : "v"(t0), "v"(t1));
      asm("v_cvt_pk_bf16_f32 %0, %1, %2" : "=v"(w1[rg]) : "v"(t2), "v"(t3));
    }
    #pragma unroll
    for (int kb = 0; kb < 2; ++kb) {
      int rs = 2 * kb;
      uint x0 = w0[rs], y0 = w0[rs + 1];
      asm("v_permlane32_swap_b32 %0, %1" : "+v"(x0), "+v"(y0));
      uint x1 = w1[rs], y1 = w1[rs + 1];
      asm("v_permlane32_swap_b32 %0, %1" : "+v"(x1), "+v"(y1));
      uint4 pk; pk.x = x0; pk.y = x1; pk.z = y0; pk.w = y1;
      paW[kb] = pk;
    }
    asm volatile("s_waitcnt vmcnt(0) lgkmcnt(0)" ::: "memory");
    __builtin_amdgcn_s_barrier();
  };

  // prologue: K(0)
  stage_k(0, 0);
  asm volatile("s_waitcnt vmcnt(0) lgkmcnt(0)" ::: "memory");
  __builtin_amdgcn_s_barrier();

  body(0, 0, paA, paB, false, true);
  for (int t2 = 0; t2 < 31; ++t2) {
    body(2 * t2 + 1, 1, paB, paA, true, true);
    body(2 * t2 + 2, 0, paA, paB, true, true);
  }
  body(63, 1, paB, paA, true, false);
  // drain: PV(63) from V buffer 1, paB
  do_pv(1, paB);

  // ---- cross-n-half reduction through LDS (once) ----
  __syncthreads();
  float* red = (float*)&SM[0];
  if (nh == 1) {
    #pragma unroll
    for (int et = 0; et < 4; ++et)
      #pragma unroll
      for (int rg4 = 0; rg4 < 4; ++rg4) {
        float4 w;
        w.x = acc[et][4*rg4+0]; w.y = acc[et][4*rg4+1];
        w.z = acc[et][4*rg4+2]; w.w = acc[et][4*rg4+3];
        *(float4*)&red[wg * 4096 + et * 1024 + rg4 * 256 + lane * 4] = w;
      }
  }
  __syncthreads();
  if (nh == 0) {
    #pragma unroll
    for (int et = 0; et < 4; ++et)
      #pragma unroll
      for (int rg4 = 0; rg4 < 4; ++rg4) {
        float4 r = *(const float4*)&red[wg * 4096 + et * 1024 + rg4 * 256 + lane * 4];
        acc[et][4*rg4+0] += r.x; acc[et][4*rg4+1] += r.y;
        acc[et][4*rg4+2] += r.z; acc[et][4*rg4+3] += r.w;
      }
    // ---- epilogue: KVU = bf16(u * acc); D: col=e(l31), row m=(reg&3)+8(reg>>2)+4hi ----
    #pragma unroll
    for (int et = 0; et < 4; ++et)
      #pragma unroll
      for (int reg = 0; reg < 16; ++reg) {
        int ml = (reg & 3) + 8 * (reg >> 2) + 4 * hi;
        size_t grow = (size_t)b * N_ + m0 + wg * 32 + ml;
        size_t ge = e0 + et * 32 + l31;
        float uu = b2f(U[grow * E_ + ge]);
        KVU[grow * E_ + ge] = f2b(uu * acc[et][reg]);
      }
  }
}

extern "C" void kernel_launch(void* const* d_in, const int* in_sizes, int n_in,
                              void* d_out, int out_size, void* d_ws, size_t ws_size,
                              hipStream_t stream) {
  const float* query = (const float*)d_in[0];
  const float* ln_w  = (const float*)d_in[1];
  const float* ln_b  = (const float*)d_in[2];
  const float* Wu    = (const float*)d_in[3];
  const float* bu    = (const float*)d_in[4];
  const float* Wv    = (const float*)d_in[5];
  const float* bv    = (const float*)d_in[6];
  const float* Wbase = (const float*)d_in[7];
  const float* bbase = (const float*)d_in[8];
  const float* q_w   = (const float*)d_in[9];
  const float* q_b   = (const float*)d_in[10];
  const float* k_w   = (const float*)d_in[11];
  const float* k_b   = (const float*)d_in[12];
  const float* w_rel = (const float*)d_in[13];
  const float* Wo    = (const float*)d_in[14];
  const float* bo    = (const float*)d_in[15];
  float* out = (float*)d_out;

  char* ws = (char*)d_ws;
  ushort* X    = (ushort*)(ws);                     // 8192*256  (4 MB); reused as WREP after gemms
  ushort* U    = (ushort*)(ws + (4u  << 20));       // 8192*512  (8 MB)
  ushort* VT   = (ushort*)(ws + (12u << 20));       // 512*8192  (8 MB)
  ushort* BASE = (ushort*)(ws + (20u << 20));       // 8192*128  (2 MB)
  ushort* Qb   = (ushort*)(ws + (22u << 20));       // 2 MB
  ushort* Kb   = (ushort*)(ws + (24u << 20));       // 2 MB
  ushort* KVU  = (ushort*)(ws + (26u << 20));       // 8 MB
  ushort* WUT  = (ushort*)(ws + (34u << 20));
  ushort* WVT  = (ushort*)(ws + (34u << 20) + 512*256*2);
  ushort* WBT  = (ushort*)(ws + (34u << 20) + 2*512*256*2);
  ushort* WOT  = (ushort*)(ws + (34u << 20) + 2*512*256*2 + 128*256*2);
  float*  WREP = (float*)(ws);                      // 128 KB, written after X is dead

  ln_kernel<<<2048, 256, 0, stream>>>(query, ln_w, ln_b, X);
  wt_kernel<<<(512*256 + 255) / 256, 256, 0, stream>>>(Wu, WUT, 256, 512);
  wt_kernel<<<(512*256 + 255) / 256, 256, 0, stream>>>(Wv, WVT, 256, 512);
  wt_kernel<<<(128*256 + 255) / 256, 256, 0, stream>>>(Wbase, WBT, 256, 128);
  wt_kernel<<<(512*256 + 255) / 256, 256, 0, stream>>>(Wo, WOT, 512, 256);
  gemm_kernel<0><<<dim3(64, 8), 256, 0, stream>>>(X, WUT, bu, U, 8192, 512, 256);
  gemm_kernel<2><<<dim3(64, 8), 256, 0, stream>>>(X, WVT, bv, VT, 8192, 512, 256);
  gemm_kernel<0><<<dim3(64, 2), 256, 0, stream>>>(X, WBT, bbase, BASE, 8192, 128, 256);
  wrep_kernel<<<128, 256, 0, stream>>>(w_rel, WREP);   // X dead from here
  rope_kernel<<<2048, 256, 0, stream>>>(BASE, q_w, q_b, k_w, k_b, Qb, Kb);
  attn_kernel<<<dim3(32, 4, 2), 512, 0, stream>>>(Qb, Kb, VT, U, WREP, KVU);
  gemm_kernel<1><<<dim3(64, 4), 256, 0, stream>>>(KVU, WOT, bo, out, 8192, 256, 512);
}

// Round 11
// 161.164 us; speedup vs baseline: 1.8024x; 1.0624x over previous
//
#include <hip/hip_runtime.h>
#include <hip/hip_bf16.h>
#include <math.h>

typedef __bf16 bf16_8 __attribute__((ext_vector_type(8)));
typedef float f32x4 __attribute__((ext_vector_type(4)));

#define D_ 256
#define S_ 128
#define E_ 512
#define MPE_ 4096
#define B_ 2
#define N_ 4096
#define M_TOT (B_*N_)   // 8192

__device__ __forceinline__ ushort f2b(float f) {
  union { float f; uint u; } x; x.f = f;
  uint r = (x.u + 0x7FFFu + ((x.u >> 16) & 1u)) >> 16;
  return (ushort)r;
}
__device__ __forceinline__ float b2f(ushort b) {
  union { uint u; float f; } x; x.u = ((uint)b) << 16;
  return x.f;
}

__device__ __forceinline__ void gl_lds16(const void* g, void* l) {
  __builtin_amdgcn_global_load_lds(
      (const __attribute__((address_space(1))) void*)g,
      (__attribute__((address_space(3))) void*)l, 16, 0, 0);
}

// ---------------- LayerNorm: one wave per row ----------------
__global__ __launch_bounds__(256) void ln_kernel(const float* __restrict__ q,
    const float* __restrict__ w, const float* __restrict__ b,
    ushort* __restrict__ x) {
  int wid = threadIdx.x >> 6, lane = threadIdx.x & 63;
  int row = blockIdx.x * 4 + wid;
  const float* qr = q + (size_t)row * D_;
  float4 v = *(const float4*)(qr + lane * 4);
  float s  = v.x + v.y + v.z + v.w;
  float ss = v.x*v.x + v.y*v.y + v.z*v.z + v.w*v.w;
  #pragma unroll
  for (int off = 32; off; off >>= 1) {
    s  += __shfl_xor(s, off);
    ss += __shfl_xor(ss, off);
  }
  float mu   = s * (1.0f / 256.0f);
  float var  = ss * (1.0f / 256.0f) - mu * mu;
  float rstd = rsqrtf(var + 1e-5f);
  ushort4 o;
  float vv[4] = {v.x, v.y, v.z, v.w};
  ushort ot[4];
  #pragma unroll
  for (int j = 0; j < 4; ++j) {
    int c = lane * 4 + j;
    ot[j] = f2b((vv[j] - mu) * rstd * w[c] + b[c]);
  }
  o.x = ot[0]; o.y = ot[1]; o.z = ot[2]; o.w = ot[3];
  *(ushort4*)(x + (size_t)row * D_ + lane * 4) = o;
}

// ---------------- prep: all 4 weight transposes + wrep in ONE launch ----------------
__global__ __launch_bounds__(256) void prep_kernel(
    const float* __restrict__ Wu, const float* __restrict__ Wv,
    const float* __restrict__ Wb, const float* __restrict__ Wo,
    const float* __restrict__ w_rel,
    ushort* __restrict__ WUT, ushort* __restrict__ WVT,
    ushort* __restrict__ WBT, ushort* __restrict__ WOT,
    float* __restrict__ wrep) {
  int blk = blockIdx.x, tid = threadIdx.x;
  if (blk < 512) {                        // WUT: [512][256] <- Wu [256][512]
    int o = blk * 256 + tid; int c = o >> 8, r = o & 255;
    WUT[o] = f2b(Wu[r * 512 + c]);
  } else if (blk < 1024) {                // WVT
    int o = (blk - 512) * 256 + tid; int c = o >> 8, r = o & 255;
    WVT[o] = f2b(Wv[r * 512 + c]);
  } else if (blk < 1152) {                // WBT: [128][256] <- Wbase [256][128]
    int o = (blk - 1024) * 256 + tid; int c = o >> 8, r = o & 255;
    WBT[o] = f2b(Wb[r * 128 + c]);
  } else if (blk < 1664) {                // WOT: [256][512] <- Wo [512][256]
    int o = (blk - 1152) * 256 + tid; int c = o >> 9, r = o & 511;
    WOT[o] = f2b(Wo[r * 256 + c]);
  } else {                                // wrep[c][i] = w_rel[min(i+c,8190)]
    int idx = (blk - 1664) * 256 + tid;
    int c = idx >> 13, i = idx & 8191;
    int s = i + c; if (s > 8190) s = 8190;
    wrep[idx] = w_rel[s];
  }
}

// ---------------- GEMM: A[M][K] bf16, Bt[N][K] bf16, tile 128x64, BK=64 ----------------
template<int EPI>
__global__ __launch_bounds__(256) void gemm_kernel(
    const ushort* __restrict__ A, const ushort* __restrict__ Bt,
    const float* __restrict__ bias, void* __restrict__ out,
    int M, int N, int K) {
  __shared__ alignas(16) ushort As[128 * 64];
  __shared__ alignas(16) ushort Bs[64 * 64];
  int tid = threadIdx.x;
  int lane = tid & 63, wid = tid >> 6;
  int m0 = blockIdx.x * 128, n0 = blockIdx.y * 64;
  int r16 = lane & 15, kq = lane >> 4;
  f32x4 acc[2][4] = {};
  for (int k0 = 0; k0 < K; k0 += 64) {
    __syncthreads();
    #pragma unroll
    for (int t = 0; t < 4; ++t) {
      int cid = tid + t * 256;
      int row = cid >> 3, c = cid & 7;
      uint4 d = *(const uint4*)(A + ((size_t)(m0 + row) * K + k0 + c * 8));
      *(uint4*)&As[row * 64 + ((c ^ (row & 7)) * 8)] = d;
    }
    #pragma unroll
    for (int t = 0; t < 2; ++t) {
      int cid = tid + t * 256;
      int row = cid >> 3, c = cid & 7;
      uint4 d = *(const uint4*)(Bt + ((size_t)(n0 + row) * K + k0 + c * 8));
      *(uint4*)&Bs[row * 64 + ((c ^ (row & 7)) * 8)] = d;
    }
    __syncthreads();
    #pragma unroll
    for (int ks = 0; ks < 2; ++ks) {
      bf16_8 af[2], bfr[4];
      int c = ks * 4 + kq;
      #pragma unroll
      for (int fm = 0; fm < 2; ++fm) {
        int r = wid * 32 + fm * 16 + r16;
        af[fm] = *(const bf16_8*)&As[r * 64 + ((c ^ (r & 7)) * 8)];
      }
      #pragma unroll
      for (int fn = 0; fn < 4; ++fn) {
        int r = fn * 16 + r16;
        bfr[fn] = *(const bf16_8*)&Bs[r * 64 + ((c ^ (r & 7)) * 8)];
      }
      #pragma unroll
      for (int fm = 0; fm < 2; ++fm)
        #pragma unroll
        for (int fn = 0; fn < 4; ++fn)
          acc[fm][fn] = __builtin_amdgcn_mfma_f32_16x16x32_bf16(af[fm], bfr[fn], acc[fm][fn], 0, 0, 0);
    }
  }
  #pragma unroll
  for (int fm = 0; fm < 2; ++fm)
    #pragma unroll
    for (int fn = 0; fn < 4; ++fn)
      #pragma unroll
      for (int reg = 0; reg < 4; ++reg) {
        int ml = wid * 32 + fm * 16 + kq * 4 + reg;
        int nl = fn * 16 + r16;
        size_t gm = m0 + ml, gn = n0 + nl;
        float val = acc[fm][fn][reg] + bias[gn];
        if (EPI == 0) {
          float y = val / (1.0f + expf(-val));
          ((ushort*)out)[gm * N + gn] = f2b(y);
        } else if (EPI == 2) {
          float y = val / (1.0f + expf(-val));
          ((ushort*)out)[gn * (size_t)M_TOT + gm] = f2b(y);
        } else {
          ((float*)out)[gm * N + gn] = val;
        }
      }
}

// ---------------- RoPE (outputs pre-scaled by 1/64 so q.k carries 1/MPE) ----------------
__global__ __launch_bounds__(256) void rope_kernel(const ushort* __restrict__ base,
    const float* __restrict__ qw, const float* __restrict__ qb,
    const float* __restrict__ kw, const float* __restrict__ kb,
    ushort* __restrict__ Q, ushort* __restrict__ Kk) {
  int g = blockIdx.x * 256 + threadIdx.x;
  int row = g >> 6, i = g & 63;
  int n = row & (N_ - 1);
  float invf = powf(10000.0f, -(float)i * (1.0f / 64.0f));
  float sv, cv;
  sincosf((float)n * invf, &sv, &cv);
  const float sc = 0.015625f;   // 1/64; (1/64)^2 = 1/4096 = 1/MPE
  float b1 = b2f(base[row * S_ + i]), b2 = b2f(base[row * S_ + 64 + i]);
  float x1q = b1 * qw[i] + qb[i], x2q = b2 * qw[64 + i] + qb[64 + i];
  Q[row * S_ + i]      = f2b((x1q * cv - x2q * sv) * sc);
  Q[row * S_ + 64 + i] = f2b((x2q * cv + x1q * sv) * sc);
  float x1k = b1 * kw[i] + kb[i], x2k = b2 * kw[64 + i] + kb[64 + i];
  Kk[row * S_ + i]      = f2b((x1k * cv - x2k * sv) * sc);
  Kk[row * S_ + 64 + i] = f2b((x2k * cv + x1k * sv) * sc);
}

// ---------------- fused attention: R6 pipeline, 2 independent blocks per CU ----------------
// grid (64 m-tiles of 64, 4 e-chunks of 128, 2 b) = 512 blocks, 256 thr (4 waves),
// 72 KB LDS -> 2 blocks/CU (two independent barrier domains that anti-phase).
// Iter t: stage K(t+1), V(t); QK(t) -> sacc; PV(t-1) from Pb/V(t-1);
// lgkm-only mid barrier; transform -> Pb (single-buffered); end barrier drains vmcnt.
// QK waves: 1m-group x 4n (kf reused 4x over fm); PV waves: 2m x 2e.
// Bias: one aligned float4 per fm via wrep's 4 shifted copies.
__global__ __launch_bounds__(256, 2) void attn_kernel(
    const ushort* __restrict__ Q, const ushort* __restrict__ Kd,
    const ushort* __restrict__ VT, const ushort* __restrict__ U,
    const float* __restrict__ wrep, ushort* __restrict__ KVU) {
  __shared__ alignas(16) ushort Ks[2][64 * 128];   // 32 KB
  __shared__ alignas(16) ushort Vs[2][128 * 64];   // 32 KB
  __shared__ alignas(16) ushort Pb[64 * 64];       // 8 KB (single-buffered)
  const int tid = threadIdx.x, lane = tid & 63, wid = tid >> 6;
  const int b = blockIdx.z, m0 = blockIdx.x * 64, e0 = blockIdx.y * 128;
  const int r16 = lane & 15, kq = lane >> 4;
  const int wn = wid;                      // QK: 16n strip per wave, all 64m
  const int wpm = wid >> 1, wpe = wid & 1; // PV: 2m x 2e

  // bias: w_rel idx = 4095 + (64t + 16wn + 4kq + rg) - (m0 + 16fm + r16)
  const int bbase = 4095 + 16 * wn + 4 * kq - m0 - r16;
  const int csel = bbase & 3;
  const float* wrow = wrep + csel * 8192 + (bbase - csel);

  // Q fragments: 64 m-rows x 128 k per wave (B-operand: col=m)
  bf16_8 qf[4][4];
  #pragma unroll
  for (int fm = 0; fm < 4; ++fm)
    #pragma unroll
    for (int ks = 0; ks < 4; ++ks)
      qf[fm][ks] = *(const bf16_8*)(Q +
          ((size_t)(b * N_ + m0 + fm * 16 + r16) * S_ + ks * 32 + kq * 8));

  auto stage_k = [&](int bi, int nt) {
    int n0s = nt * 64;
    #pragma unroll
    for (int tt = 0; tt < 4; ++tt) {           // K tile: 64n x 128k = 1024 chunks
      int p = tt * 256 + tid;
      int row = p >> 4, sc2 = p & 15;
      int cc = sc2 ^ (row & 7);
      gl_lds16(Kd + ((size_t)(b * N_ + n0s + row) * S_ + cc * 8),
               (char*)&Ks[bi][0] + (tt * 256 + wid * 64) * 16);
    }
  };
  auto stage_v = [&](int bi, int nt) {
    int n0s = nt * 64;
    #pragma unroll
    for (int tt = 0; tt < 4; ++tt) {           // V^T tile: 128e x 64n = 1024 chunks
      int p = tt * 256 + tid;
      int er = p >> 3, sc2 = p & 7;
      int nc = sc2 ^ (er & 7);
      gl_lds16(VT + ((size_t)(e0 + er) * M_TOT + b * N_ + n0s + nc * 8),
               (char*)&Vs[bi][0] + (tt * 256 + wid * 64) * 16);
    }
  };

  f32x4 pv[2][4] = {};
  const char* psb = (const char*)&Pb[0];

  auto do_pv = [&](int vb) {
    const ushort* vsb = &Vs[vb][0];
    __builtin_amdgcn_s_setprio(1);
    #pragma unroll
    for (int ks = 0; ks < 2; ++ks) {
      bf16_8 pa[2];
      #pragma unroll
      for (int fm = 0; fm < 2; ++fm) {
        int r = wpm * 32 + fm * 16 + r16;
        pa[fm] = *(const bf16_8*)(psb + ((r * 128 + ks * 64 + kq * 16) ^ ((r & 7) << 4)));
      }
      #pragma unroll
      for (int fe = 0; fe < 4; ++fe) {
        int rv = wpe * 64 + fe * 16 + r16;
        int cv = ks * 4 + kq;
        bf16_8 vf = *(const bf16_8*)&vsb[rv * 64 + ((cv ^ (rv & 7)) * 8)];
        #pragma unroll
        for (int fm = 0; fm < 2; ++fm)
          pv[fm][fe] = __builtin_amdgcn_mfma_f32_16x16x32_bf16(pa[fm], vf, pv[fm][fe], 0, 0, 0);
      }
    }
    __builtin_amdgcn_s_setprio(0);
  };

  // prologue: K(0)
  stage_k(0, 0);
  asm volatile("s_waitcnt vmcnt(0) lgkmcnt(0)" ::: "memory");
  __builtin_amdgcn_s_barrier();

  auto body = [&](int t, int cur, bool doK) {
    // ---- bias: 4 aligned float4 (early VMEM issue) ----
    float4 b4[4];
    #pragma unroll
    for (int fm = 0; fm < 4; ++fm)
      b4[fm] = *(const float4*)(wrow + 64 * t - 16 * fm);
    // ---- stage K(t+1), V(t) ----
    if (doK) stage_k(cur ^ 1, t + 1);
    stage_v(cur, t);
    __builtin_amdgcn_sched_barrier(0);
    // ---- QK (swapped): sacc[fm] = K_frag x Q_frag -> col=m, rows=n ----
    const ushort* ksb = &Ks[cur][0];
    f32x4 sacc[4] = {};
    __builtin_amdgcn_s_setprio(1);
    #pragma unroll
    for (int ks = 0; ks < 4; ++ks) {
      int r = wn * 16 + r16;
      int c = ks * 4 + kq;
      bf16_8 kf = *(const bf16_8*)&ksb[r * 128 + ((c ^ (r & 7)) * 8)];
      #pragma unroll
      for (int fm = 0; fm < 4; ++fm)
        sacc[fm] = __builtin_amdgcn_mfma_f32_16x16x32_bf16(kf, qf[fm][ks], sacc[fm], 0, 0, 0);
    }
    __builtin_amdgcn_s_setprio(0);
    // ---- PV(t-1): reads Pb (P(t-1)) + Vs[cur^1] (V(t-1)) ----
    if (t > 0) do_pv(cur ^ 1);
    // ---- mid barrier: all waves done READING Pb (lgkm only; vmcnt stays live) ----
    asm volatile("s_waitcnt lgkmcnt(0)" ::: "memory");
    __builtin_amdgcn_s_barrier();
    // ---- transform -> Pb (packed uint2 writes) ----
    #pragma unroll
    for (int fm = 0; fm < 4; ++fm) {
      float t0 = fmaxf(sacc[fm][0] + b4[fm].x, 0.f); t0 *= t0;
      float t1 = fmaxf(sacc[fm][1] + b4[fm].y, 0.f); t1 *= t1;
      float t2 = fmaxf(sacc[fm][2] + b4[fm].z, 0.f); t2 *= t2;
      float t3 = fmaxf(sacc[fm][3] + b4[fm].w, 0.f); t3 *= t3;
      uint p01, p23;
      asm("v_cvt_pk_bf16_f32 %0, %1, %2" : "=v"(p01) : "v"(t0), "v"(t1));
      asm("v_cvt_pk_bf16_f32 %0, %1, %2" : "=v"(p23) : "v"(t2), "v"(t3));
      int mp = fm * 16 + r16;
      int nb2 = wn * 32 + kq * 8;
      uint2 pk; pk.x = p01; pk.y = p23;
      *(uint2*)((char*)&Pb[0] + ((mp * 128 + nb2) ^ ((mp & 7) << 4))) = pk;
    }
    // ---- end barrier: staging landed + P visible ----
    asm volatile("s_waitcnt vmcnt(0) lgkmcnt(0)" ::: "memory");
    __builtin_amdgcn_s_barrier();
  };

  for (int t2 = 0; t2 < 32; ++t2) {
    body(2 * t2, 0, true);
    body(2 * t2 + 1, 1, 2 * t2 + 1 < 63);
  }
  // drain: PV(63) from Pb + Vs[1]
  do_pv(1);

  // ---- epilogue: KVU = bf16(u * pv) ----
  #pragma unroll
  for (int fm = 0; fm < 2; ++fm)
    #pragma unroll
    for (int fe = 0; fe < 4; ++fe)
      #pragma unroll
      for (int reg = 0; reg < 4; ++reg) {
        int ml = wpm * 32 + fm * 16 + kq * 4 + reg;
        size_t grow = (size_t)b * N_ + m0 + ml;
        size_t ge = e0 + wpe * 64 + fe * 16 + r16;
        float uu = b2f(U[grow * E_ + ge]);
        KVU[grow * E_ + ge] = f2b(uu * pv[fm][fe][reg]);
      }
}

extern "C" void kernel_launch(void* const* d_in, const int* in_sizes, int n_in,
                              void* d_out, int out_size, void* d_ws, size_t ws_size,
                              hipStream_t stream) {
  const float* query = (const float*)d_in[0];
  const float* ln_w  = (const float*)d_in[1];
  const float* ln_b  = (const float*)d_in[2];
  const float* Wu    = (const float*)d_in[3];
  const float* bu    = (const float*)d_in[4];
  const float* Wv    = (const float*)d_in[5];
  const float* bv    = (const float*)d_in[6];
  const float* Wbase = (const float*)d_in[7];
  const float* bbase = (const float*)d_in[8];
  const float* q_w   = (const float*)d_in[9];
  const float* q_b   = (const float*)d_in[10];
  const float* k_w   = (const float*)d_in[11];
  const float* k_b   = (const float*)d_in[12];
  const float* w_rel = (const float*)d_in[13];
  const float* Wo    = (const float*)d_in[14];
  const float* bo    = (const float*)d_in[15];
  float* out = (float*)d_out;

  char* ws = (char*)d_ws;
  ushort* X    = (ushort*)(ws);                     // 8192*256  (4 MB)
  ushort* U    = (ushort*)(ws + (4u  << 20));       // 8192*512  (8 MB)
  ushort* VT   = (ushort*)(ws + (12u << 20));       // 512*8192  (8 MB)
  ushort* BASE = (ushort*)(ws + (20u << 20));       // 8192*128  (2 MB)
  ushort* Qb   = (ushort*)(ws + (22u << 20));       // 2 MB
  ushort* Kb   = (ushort*)(ws + (24u << 20));       // 2 MB
  ushort* KVU  = (ushort*)(ws + (26u << 20));       // 8 MB
  ushort* WUT  = (ushort*)(ws + (34u << 20));
  ushort* WVT  = (ushort*)(ws + (34u << 20) + 512*256*2);
  ushort* WBT  = (ushort*)(ws + (34u << 20) + 2*512*256*2);
  ushort* WOT  = (ushort*)(ws + (34u << 20) + 2*512*256*2 + 128*256*2);
  float*  WREP = (float*)(ws + (35u << 20));        // 128 KB

  ln_kernel<<<2048, 256, 0, stream>>>(query, ln_w, ln_b, X);
  prep_kernel<<<1792, 256, 0, stream>>>(Wu, Wv, Wbase, Wo, w_rel,
                                        WUT, WVT, WBT, WOT, WREP);
  gemm_kernel<0><<<dim3(64, 8), 256, 0, stream>>>(X, WUT, bu, U, 8192, 512, 256);
  gemm_kernel<2><<<dim3(64, 8), 256, 0, stream>>>(X, WVT, bv, VT, 8192, 512, 256);
  gemm_kernel<0><<<dim3(64, 2), 256, 0, stream>>>(X, WBT, bbase, BASE, 8192, 128, 256);
  rope_kernel<<<2048, 256, 0, stream>>>(BASE, q_w, q_b, k_w, k_b, Qb, Kb);
  attn_kernel<<<dim3(64, 4, 2), 256, 0, stream>>>(Qb, Kb, VT, U, WREP, KVU);
  gemm_kernel<1><<<dim3(64, 4), 256, 0, stream>>>(KVU, WOT, bo, out, 8192, 256, 512);
}